// Round 1
// baseline (335.268 us; speedup 1.0000x reference)
//
#include <hip/hip_runtime.h>
#include <math.h>

// Sizes fixed by the problem.
#define N_AG   512
#define HIDD   256
#define OBSD   128
// P = 512*511/2 = 130816 pairs, out = [P,3]

__device__ __forceinline__ float dot4(float4 a, float4 b){
    return a.x*b.x + a.y*b.y + a.z*b.z + a.w*b.w;
}

// ---------------- K1: hid = relu(inputs @ fc1_w.T + fc1_b) ----------------
// grid (4 output-tiles of 64, 64 agent-tiles of 8), 256 threads
__global__ __launch_bounds__(256) void k_fc1(const float* __restrict__ in,
        const float* __restrict__ w, const float* __restrict__ b,
        float* __restrict__ hid){
    __shared__ float lin[8*OBSD];
    int at = blockIdx.y, ot = blockIdx.x, t = threadIdx.x;
    ((float4*)lin)[t] = ((const float4*)(in + at*8*OBSD))[t];   // 8x128 = 256 float4
    __syncthreads();
    int ol = t & 63, g = t >> 6;
    int o = ot*64 + ol;
    const float4* w4 = (const float4*)(w + o*OBSD);
    const float4* la = (const float4*)(lin + (g*2)*OBSD);
    const float4* lb = (const float4*)(lin + (g*2+1)*OBSD);
    float acc0 = 0.f, acc1 = 0.f;
    #pragma unroll
    for (int c = 0; c < OBSD/4; ++c){
        float4 wv = w4[c];
        acc0 += dot4(la[c], wv);
        acc1 += dot4(lb[c], wv);
    }
    float bb = b[o];
    int a0 = at*8 + g*2;
    hid[a0*HIDD + o]     = fmaxf(acc0 + bb, 0.f);
    hid[(a0+1)*HIDD + o] = fmaxf(acc1 + bb, 0.f);
}

// ---------------- K2: qkv = hid @ in_proj_w.T + in_proj_b ----------------
// grid (12 output-tiles of 64, 64 agent-tiles of 8), 256 threads
__global__ __launch_bounds__(256) void k_qkv(const float* __restrict__ hid,
        const float* __restrict__ w, const float* __restrict__ b,
        float* __restrict__ qkv){
    __shared__ float lin[8*HIDD];
    int at = blockIdx.y, ot = blockIdx.x, t = threadIdx.x;
    const float4* in4 = (const float4*)(hid + at*8*HIDD);
    ((float4*)lin)[t]       = in4[t];
    ((float4*)lin)[t + 256] = in4[t + 256];
    __syncthreads();
    int ol = t & 63, g = t >> 6;
    int o = ot*64 + ol;                       // 0..767
    const float4* w4 = (const float4*)(w + o*HIDD);
    const float4* la = (const float4*)(lin + (g*2)*HIDD);
    const float4* lb = (const float4*)(lin + (g*2+1)*HIDD);
    float acc0 = 0.f, acc1 = 0.f;
    #pragma unroll 16
    for (int c = 0; c < HIDD/4; ++c){
        float4 wv = w4[c];
        acc0 += dot4(la[c], wv);
        acc1 += dot4(lb[c], wv);
    }
    float bb = b[o];
    int a0 = at*8 + g*2;
    qkv[a0*768 + o]     = acc0 + bb;
    qkv[(a0+1)*768 + o] = acc1 + bb;
}

// ---------------- K3: attention + out_proj, 2 query rows per block ----------------
__global__ __launch_bounds__(256) void k_attn(const float* __restrict__ qkv,
        const float* __restrict__ ow, const float* __restrict__ ob,
        float* __restrict__ hout){
    __shared__ float q2[2*HIDD];
    __shared__ float sc[2*512];
    __shared__ float av[2*HIDD];
    __shared__ float red[16];
    int r0 = blockIdx.x*2, t = threadIdx.x;
    if (t < 128){
        int r = t >> 6, c4 = t & 63;
        ((float4*)q2)[r*64 + c4] = ((const float4*)(qkv + (r0+r)*768))[c4];
    }
    __syncthreads();
    // scores for j = t and t+256, both rows
    #pragma unroll
    for (int jj = 0; jj < 2; ++jj){
        int j = t + jj*256;
        const float4* k4 = (const float4*)(qkv + j*768 + HIDD);
        const float4* qa = (const float4*)q2;
        const float4* qb = (const float4*)(q2 + HIDD);
        float a0 = 0.f, a1 = 0.f;
        #pragma unroll 16
        for (int c = 0; c < HIDD/4; ++c){
            float4 kv = k4[c];
            a0 += dot4(qa[c], kv);
            a1 += dot4(qb[c], kv);
        }
        sc[j]       = a0 * 0.0625f;   // 1/sqrt(256)
        sc[512 + j] = a1 * 0.0625f;
    }
    __syncthreads();
    // softmax, both rows in one pass
    int lane = t & 63, wid = t >> 6;
    float s00 = sc[t], s01 = sc[t+256], s10 = sc[512+t], s11 = sc[512+t+256];
    float m0 = fmaxf(s00, s01), m1 = fmaxf(s10, s11);
    for (int off = 32; off; off >>= 1){
        m0 = fmaxf(m0, __shfl_xor(m0, off));
        m1 = fmaxf(m1, __shfl_xor(m1, off));
    }
    if (lane == 0){ red[wid] = m0; red[4+wid] = m1; }
    __syncthreads();
    m0 = fmaxf(fmaxf(red[0],red[1]), fmaxf(red[2],red[3]));
    m1 = fmaxf(fmaxf(red[4],red[5]), fmaxf(red[6],red[7]));
    float e00 = expf(s00-m0), e01 = expf(s01-m0), e10 = expf(s10-m1), e11 = expf(s11-m1);
    float t0 = e00+e01, t1 = e10+e11;
    for (int off = 32; off; off >>= 1){ t0 += __shfl_xor(t0, off); t1 += __shfl_xor(t1, off); }
    if (lane == 0){ red[8+wid] = t0; red[12+wid] = t1; }
    __syncthreads();
    float inv0 = 1.f/(red[8]+red[9]+red[10]+red[11]);
    float inv1 = 1.f/(red[12]+red[13]+red[14]+red[15]);
    sc[t] = e00*inv0; sc[t+256] = e01*inv0;
    sc[512+t] = e10*inv1; sc[512+t+256] = e11*inv1;
    __syncthreads();
    // av = attn @ v  (v reads coalesced across t)
    {
        float acc0 = 0.f, acc1 = 0.f;
        for (int j = 0; j < 512; ++j){
            float vv = qkv[j*768 + 512 + t];
            acc0 += sc[j]*vv;
            acc1 += sc[512+j]*vv;
        }
        av[t] = acc0; av[HIDD+t] = acc1;
    }
    __syncthreads();
    // h = av @ out_proj_w.T + ob
    {
        const float4* w4 = (const float4*)(ow + t*HIDD);
        const float4* a4 = (const float4*)av;
        const float4* b4 = (const float4*)(av + HIDD);
        float h0 = 0.f, h1 = 0.f;
        #pragma unroll 16
        for (int c = 0; c < HIDD/4; ++c){
            float4 wv = w4[c];
            h0 += dot4(a4[c], wv);
            h1 += dot4(b4[c], wv);
        }
        float bb = ob[t];
        hout[r0*HIDD + t]     = h0 + bb;
        hout[(r0+1)*HIDD + t] = h1 + bb;
    }
}

// ---------------- K4: A = h @ fc2_w[:, :256].T + fc2_b ; B = h @ fc2_w[:, 256:].T ----------------
// grid (8 output-tiles of 64 -> o2 in 0..511, 64 agent-tiles of 8), 256 threads
__global__ __launch_bounds__(256) void k_ab(const float* __restrict__ hin,
        const float* __restrict__ w, const float* __restrict__ b,
        float* __restrict__ A, float* __restrict__ B){
    __shared__ float lin[8*HIDD];
    int at = blockIdx.y, ot = blockIdx.x, t = threadIdx.x;
    const float4* in4 = (const float4*)(hin + at*8*HIDD);
    ((float4*)lin)[t]       = in4[t];
    ((float4*)lin)[t + 256] = in4[t + 256];
    __syncthreads();
    int ol = t & 63, g = t >> 6;
    int o2 = ot*64 + ol;                       // 0..511
    bool isA = o2 < HIDD;
    int o = isA ? o2 : o2 - HIDD;
    const float4* w4 = (const float4*)(w + o*512 + (isA ? 0 : HIDD));
    const float4* la = (const float4*)(lin + (g*2)*HIDD);
    const float4* lb = (const float4*)(lin + (g*2+1)*HIDD);
    float acc0 = 0.f, acc1 = 0.f;
    #pragma unroll 16
    for (int c = 0; c < HIDD/4; ++c){
        float4 wv = w4[c];
        acc0 += dot4(la[c], wv);
        acc1 += dot4(lb[c], wv);
    }
    int a0 = at*8 + g*2;
    float* dst = isA ? A : B;
    float bb = isA ? b[o] : 0.f;               // fold fc2_b into A
    dst[a0*HIDD + o]     = acc0 + bb;
    dst[(a0+1)*HIDD + o] = acc1 + bb;
}

// ---------------- K5a: value-head partials (streams 134 MB of vfc2_w) ----------------
// grid (8 chunks, 256 outputs), 256 threads; chunk = 16384 floats of the 131072-row
__global__ __launch_bounds__(256) void k_vpart(const float* __restrict__ hid,
        const float* __restrict__ vw, float* __restrict__ partial){
    int chunk = blockIdx.x, o = blockIdx.y, t = threadIdx.x;
    const float4* h4 = (const float4*)hid;
    const float4* w4 = (const float4*)vw;
    long base  = (long)chunk*4096;             // float4 units
    long wbase = (long)o*32768 + base;
    float acc = 0.f;
    #pragma unroll 4
    for (int it = 0; it < 16; ++it){
        acc += dot4(h4[base + it*256 + t], w4[wbase + it*256 + t]);
    }
    for (int off = 32; off; off >>= 1) acc += __shfl_xor(acc, off);
    __shared__ float red[4];
    int lane = t & 63, wid = t >> 6;
    if (lane == 0) red[wid] = acc;
    __syncthreads();
    if (t == 0) partial[o*8 + chunk] = red[0]+red[1]+red[2]+red[3];
}

// ---------------- K5b: value scalar ----------------
__global__ __launch_bounds__(256) void k_value(const float* __restrict__ partial,
        const float* __restrict__ vb, const float* __restrict__ v3w,
        const float* __restrict__ v3b, float* __restrict__ value){
    int t = threadIdx.x;
    float s = vb[t];
    #pragma unroll
    for (int c = 0; c < 8; ++c) s += partial[t*8 + c];
    s = fmaxf(s, 0.f);
    float p = s * v3w[t];
    for (int off = 32; off; off >>= 1) p += __shfl_xor(p, off);
    __shared__ float red[4];
    int lane = t & 63, wid = t >> 6;
    if (lane == 0) red[wid] = p;
    __syncthreads();
    if (t == 0) value[0] = red[0]+red[1]+red[2]+red[3] + v3b[0];
}

// ---------------- K6: per-pair x=relu(A[i]+B[j]); out = [sigmoid(wd.x+bd), 1-., value] ----------------
// grid (32,32) tiles of 16x16 pairs; LDS stride 260 floats (mod 32 = 4 -> only 2-way bank alias, free)
__global__ __launch_bounds__(256) void k_pairs(const float* __restrict__ A,
        const float* __restrict__ B, const float* __restrict__ w3,
        const float* __restrict__ b3, const float* __restrict__ value,
        float* __restrict__ out){
    int ti = blockIdx.x, tj = blockIdx.y;
    if (tj < ti) return;                       // strictly-lower tiles have no pairs
    __shared__ float la[16*260], lb[16*260], lw[256];
    int t = threadIdx.x;
    #pragma unroll
    for (int l = 0; l < 4; ++l){
        int idx = l*256 + t;
        int r = idx >> 6, c4 = idx & 63;
        ((float4*)la)[r*65 + c4] = ((const float4*)A)[(ti*16 + r)*64 + c4];
        ((float4*)lb)[r*65 + c4] = ((const float4*)B)[(tj*16 + r)*64 + c4];
    }
    lw[t] = w3[t] - w3[256 + t];               // fc3_w[0]-fc3_w[1]
    __syncthreads();
    float val = value[0];
    float bd  = b3[0] - b3[1];
    int il = t >> 4, jl = t & 15;
    int i = ti*16 + il, j = tj*16 + jl;
    if (j > i){
        const float4* a4 = (const float4*)(la + il*260);
        const float4* b4 = (const float4*)(lb + jl*260);
        const float4* w4 = (const float4*)lw;
        float acc = 0.f;
        #pragma unroll 8
        for (int c = 0; c < 64; ++c){
            float4 aa = a4[c], bb = b4[c], wv = w4[c];
            acc += fmaxf(aa.x + bb.x, 0.f)*wv.x
                 + fmaxf(aa.y + bb.y, 0.f)*wv.y
                 + fmaxf(aa.z + bb.z, 0.f)*wv.z
                 + fmaxf(aa.w + bb.w, 0.f)*wv.w;
        }
        float z = acc + bd;
        float o0 = 1.f/(1.f + expf(-z));
        int p = i*511 - (i*(i-1))/2 + (j - i - 1);
        out[3*p]   = o0;
        out[3*p+1] = 1.f - o0;
        out[3*p+2] = val;
    }
}

extern "C" void kernel_launch(void* const* d_in, const int* in_sizes, int n_in,
                              void* d_out, int out_size, void* d_ws, size_t ws_size,
                              hipStream_t stream){
    const float* inputs = (const float*)d_in[0];
    const float* fc1_w  = (const float*)d_in[1];
    const float* fc1_b  = (const float*)d_in[2];
    const float* inp_w  = (const float*)d_in[3];
    const float* inp_b  = (const float*)d_in[4];
    const float* outp_w = (const float*)d_in[5];
    const float* outp_b = (const float*)d_in[6];
    const float* fc2_w  = (const float*)d_in[7];
    const float* fc2_b  = (const float*)d_in[8];
    const float* fc3_w  = (const float*)d_in[9];
    const float* fc3_b  = (const float*)d_in[10];
    const float* vfc2_w = (const float*)d_in[11];
    const float* vfc2_b = (const float*)d_in[12];
    const float* vfc3_w = (const float*)d_in[13];
    const float* vfc3_b = (const float*)d_in[14];
    float* out = (float*)d_out;
    float* ws  = (float*)d_ws;
    // ws layout (floats): total 919553 (~3.7 MB)
    float* hid     = ws;             // 512*256
    float* qkv     = ws + 131072;    // 512*768
    float* h       = ws + 524288;    // 512*256
    float* A       = ws + 655360;    // 512*256
    float* B       = ws + 786432;    // 512*256
    float* partial = ws + 917504;    // 256*8
    float* value   = ws + 919552;    // 1

    k_fc1  <<<dim3(4, 64),  256, 0, stream>>>(inputs, fc1_w, fc1_b, hid);
    k_qkv  <<<dim3(12, 64), 256, 0, stream>>>(hid, inp_w, inp_b, qkv);
    k_attn <<<dim3(256),    256, 0, stream>>>(qkv, outp_w, outp_b, h);
    k_ab   <<<dim3(8, 64),  256, 0, stream>>>(h, fc2_w, fc2_b, A, B);
    k_vpart<<<dim3(8, 256), 256, 0, stream>>>(hid, vfc2_w, partial);
    k_value<<<1,            256, 0, stream>>>(partial, vfc2_b, vfc3_w, vfc3_b, value);
    k_pairs<<<dim3(32, 32), 256, 0, stream>>>(A, B, fc3_w, fc3_b, value, out);
}